// Round 3
// baseline (95.803 us; speedup 1.0000x reference)
//
#include <hip/hip_runtime.h>

// MVB (minimum-variance beamformer), fp32. Round 13: revert to the R10
// LDS-free global-gather kernel (best measured: ~24.5 us dispatch).
//
// R11/R12 post-mortem (DMA-staged LDS gather, measured 50 us): at 1 block/CU
// (grid 256 == CU count) with 64 KB LDS, occupancy is 4 waves/CU (10%); the
// 16 barrier-synchronized chunks each expose full DMA+L2 latency with zero
// TLP (all 256 CUs also contend for the same rf lines in L2). Bank conflicts
// (1.26M cyc) and VALU (14.5%) were as modeled — the stall was structural.
// The barrier-free global-gather below keeps 32 loads in flight per thread
// and 2 blocks/CU and is strictly better on this problem.
//
// Bench-metric note: dur_us is flat (~95-96 us) across a 2x kernel-time
// swing (24.5 vs 50 us) — the timed region is dominated by harness
// re-poison fills running at 77-81% of HBM peak (the achievable ceiling).
//
// Kernel design:
//  - 1 thread/pixel, 128 channels, no LDS, no barriers, no DMA.
//  - chunks of 16 channels: 16 coalesced drx loads -> 16 independent 8-B
//    gathers (float2 via memcpy -> global_load_dwordx2, 32 loads in flight;
//    ILP hides L1/L2 latency) -> 16 static-index window-FMA bursts.
//  - chunk size 16 == L_SUB: window indices are compile-time constants.
// Solve phase (R assembly via lag identity + diag load + rsqrt-Cholesky +
// two triangular solves) verified absmax 9.8e-4.

namespace {

constexpr int kB  = 2;
constexpr int kC  = 128;
constexpr int kNS = 1024;
constexpr int kNZ = 256;
constexpr int kNX = 128;
constexpr int kZX = kNZ * kNX;        // 32768
constexpr int kTPB = 256;

// packed upper-triangular index, l <= k, 16x16 -> 136 entries
__device__ __host__ constexpr int tri(int l, int k) {
  return l * 16 - (l * (l - 1)) / 2 + (k - l);
}

template <bool HEAD>
__device__ __forceinline__ void chunk16(
    const float* __restrict__ rfq,       // rfb + q*16*kNS
    const float* __restrict__ drxp, int cbase, float kk, float base,
    float (&F)[16], float (&win)[16], float (&head)[16], float& Sall) {
  // 16 coalesced per-channel delays (independent, deep in flight)
  float dr[16];
#pragma unroll
  for (int r = 0; r < 16; ++r) dr[r] = drxp[(size_t)(cbase + r) * kZX];

  // 16 independent 8-byte gathers from the L1/L2-resident rf rows
  float2 vv[16];
  float fr[16];
#pragma unroll
  for (int r = 0; r < 16; ++r) {
    float pos = fmaf(kk, dr[r], base);
    pos = fminf(fmaxf(pos, 0.0f), 1023.0f);
    int i0 = (int)pos;                   // pos >= 0: trunc == floor
    i0 = min(i0, kNS - 2);               // pos==1023 -> frac==1.0
    fr[r] = pos - (float)i0;
    __builtin_memcpy(&vv[r], rfq + r * kNS + i0, 8);   // v0,v1 adjacent
  }

  // window-FMA bursts; chunk aligns with L_SUB so indices are static
#pragma unroll
  for (int r = 0; r < 16; ++r) {
    float v = fmaf(fr[r], vv[r].y - vv[r].x, vv[r].x);
    Sall += v;
    F[0] = fmaf(v, v, F[0]);
    if constexpr (HEAD) {
#pragma unroll
      for (int d = 1; d <= r; ++d) F[d] = fmaf(v, win[r - d], F[d]);
      head[r] = v;
    } else {
#pragma unroll
      for (int d = 1; d < 16; ++d) F[d] = fmaf(v, win[(r - d) & 15], F[d]);
    }
    win[r] = v;
  }
}

// ---------------- Fused kernel: gather + window + solve, no LDS ------------
__global__ __launch_bounds__(kTPB, 1) void mvb_kernel(
    const float* __restrict__ rf, const float* __restrict__ t0,
    const float* __restrict__ d_tx, const float* __restrict__ d_rx,
    const float* __restrict__ fs_p, const float* __restrict__ c0_p,
    float* __restrict__ out) {
  const int tid = threadIdx.x;
  const int b = blockIdx.x >> 7;         // 256 blocks: b in {0,1}
  const int z = ((blockIdx.x & 127) << 1) + (tid >> 7);
  const int x = tid & 127;
  const int pix = (int)((size_t)b * kZX + z * kNX + x);

  const float fs = fs_p[0];
  const float c0 = c0_p[0];
  const float kk = fs / c0;
  const float base = fs * (d_tx[pix] / c0 + t0[b]);

  const float* rfb = rf + (size_t)b * kC * kNS;
  const float* drxp = d_rx + (size_t)z * kNX + x;   // + c*kZX per channel

  float F[16], win[16], head[16];
  float Sall = 0.0f;
#pragma unroll
  for (int i = 0; i < 16; ++i) F[i] = 0.0f;

  // ---- phase A: 8 chunks of 16 channels ----
  chunk16<true>(rfb, drxp, 0, kk, base, F, win, head, Sall);
#pragma unroll 1
  for (int q = 1; q < 8; ++q)
    chunk16<false>(rfb + (size_t)q * 16 * kNS, drxp, q * 16, kk, base, F, win,
                   head, Sall);
  // now: head[i] = xf[i], win[i] = xf[112+i], F[d] = sum_j xf[j]*xf[j-d]

  // ---- assemble R (unscaled; packed upper triangle) ----
  float Ru[136];
#pragma unroll
  for (int d = 0; d < 16; ++d) {
    float t0s = 0.0f;                    // tail beyond window of l=0
#pragma unroll
    for (int i = d + 1; i < 16; ++i) t0s = fmaf(win[i - d], win[i], t0s);
    Ru[tri(0, d)] = F[d] - t0s;
#pragma unroll
    for (int l = 1; l < 16 - d; ++l)
      Ru[tri(l, l + d)] = Ru[tri(l - 1, l - 1 + d)] -
                          head[l - 1] * head[l - 1 + d] +
                          win[l] * win[l + d];
  }

  // diagonal loading: += DL * trace/16
  float tr = 0.0f;
#pragma unroll
  for (int l = 0; l < 16; ++l) tr += Ru[tri(l, l)];
  const float dl = tr * (0.05f / 16.0f);
#pragma unroll
  for (int l = 0; l < 16; ++l) Ru[tri(l, l)] += dl;

  // x (unscaled window sums): X[l] = sum_{j=l}^{l+112} xf[j]
  float X[16];
  {
    float s = Sall;
#pragma unroll
    for (int i = 1; i < 16; ++i) s -= win[i];
    X[0] = s;
#pragma unroll
    for (int l = 1; l < 16; ++l) X[l] = X[l - 1] - head[l - 1] + win[l];
  }

  // ---- Cholesky R = L L^T (rsqrt form), L[i][j] at Ru[tri(j,i)] ----
  float inv[16];
#pragma unroll
  for (int j = 0; j < 16; ++j) {
    float d = Ru[tri(j, j)];
#pragma unroll
    for (int p = 0; p < j; ++p) d = fmaf(-Ru[tri(p, j)], Ru[tri(p, j)], d);
    inv[j] = rsqrtf(d);
#pragma unroll
    for (int i = j + 1; i < 16; ++i) {
      float s = Ru[tri(j, i)];
#pragma unroll
      for (int p = 0; p < j; ++p) s = fmaf(-Ru[tri(p, i)], Ru[tri(p, j)], s);
      Ru[tri(j, i)] = s * inv[j];
    }
  }

  // forward solve L y = 1
  float yv[16];
#pragma unroll
  for (int i = 0; i < 16; ++i) {
    float s = 1.0f;
#pragma unroll
    for (int j = 0; j < i; ++j) s = fmaf(-Ru[tri(j, i)], yv[j], s);
    yv[i] = s * inv[i];
  }
  // back solve L^T u = y
  float u[16];
#pragma unroll
  for (int i = 15; i >= 0; --i) {
    float s = yv[i];
#pragma unroll
    for (int j = i + 1; j < 16; ++j) s = fmaf(-Ru[tri(i, j)], u[j], s);
    u[i] = s * inv[i];
  }

  float su = 0.0f, dot = 0.0f;
#pragma unroll
  for (int i = 0; i < 16; ++i) {
    su += u[i];
    dot = fmaf(u[i], X[i], dot);
  }
  // y = dot/(M*su + 1e-10)  (matches reference up to scale algebra)
  out[pix] = dot / (113.0f * su + 1e-10f);
}

}  // namespace

extern "C" void kernel_launch(void* const* d_in, const int* in_sizes, int n_in,
                              void* d_out, int out_size, void* d_ws,
                              size_t ws_size, hipStream_t stream) {
  const float* rf   = (const float*)d_in[0];
  const float* t0   = (const float*)d_in[1];
  const float* d_tx = (const float*)d_in[2];
  const float* d_rx = (const float*)d_in[3];
  const float* fs   = (const float*)d_in[4];
  // d_in[5] = f0 (unused), d_in[7] = apod (unused by reference)
  const float* c0   = (const float*)d_in[6];
  float* out = (float*)d_out;

  hipLaunchKernelGGL(mvb_kernel, dim3(kB * kNZ / 2), dim3(kTPB), 0, stream,
                     rf, t0, d_tx, d_rx, fs, c0, out);
}